// Round 1
// baseline (215.173 us; speedup 1.0000x reference)
//
#include <hip/hip_runtime.h>
#include <hip/hip_bf16.h>
#include <math.h>

// Problem constants
constexpr int NP     = 6144;   // pulses (rows)
constexpr int DM     = 256;    // d_model
constexpr int NH     = 4;      // heads
constexpr int HD     = 64;     // head dim
constexpr int DFF    = 1024;   // ff dim
constexpr float LNEPS = 1e-5f;

// ---------------------------------------------------------------------------
// Segment bounds: pulse_to_dom_idx is sorted, so same-doc rows are contiguous.
// One thread per row, scan outward (mean segment len ~6).
// ---------------------------------------------------------------------------
__global__ void seg_kernel(const int* __restrict__ idx,
                           int* __restrict__ seg_s, int* __restrict__ seg_e) {
    int i = blockIdx.x * blockDim.x + threadIdx.x;
    if (i >= NP) return;
    int d = idx[i];
    int s = i;
    while (s > 0 && idx[s - 1] == d) --s;
    int e = i + 1;
    while (e < NP && idx[e] == d) ++e;
    seg_s[i] = s;
    seg_e[i] = e;
}

// ---------------------------------------------------------------------------
// Generic fp32 tiled GEMM: C = A[MxK] @ B[KxN] + bias, with epilogue
// EPI: 0 = none, 1 = exact GELU, 2 = += residual
// Tile 64x64, BK=16, 256 threads, 4x4 micro-tile per thread.
// All shapes divide evenly (M=6144, N in {256,768,1024}, K in {256,1024}).
// ---------------------------------------------------------------------------
constexpr int BM = 64, BN = 64, BK = 16;

template <int EPI>
__global__ __launch_bounds__(256) void gemm_kernel(
    const float* __restrict__ A, const float* __restrict__ B,
    const float* __restrict__ bias, const float* __restrict__ res,
    float* __restrict__ C, int M, int Nn, int K) {
    __shared__ float As[BK][BM + 4];   // As[k][m]
    __shared__ float Bs[BK][BN + 4];   // Bs[k][n]

    const int tid = threadIdx.x;
    const int tx = tid & 15, ty = tid >> 4;
    const int rowBase = blockIdx.y * BM;
    const int colBase = blockIdx.x * BN;

    float acc[4][4] = {};

    for (int k0 = 0; k0 < K; k0 += BK) {
        // Load A tile (64x16): thread -> (r = tid/4, 4 consecutive k)
        {
            int r = tid >> 2;
            int kk4 = (tid & 3) * 4;
            float4 av = *(const float4*)&A[(size_t)(rowBase + r) * K + k0 + kk4];
            As[kk4 + 0][r] = av.x;
            As[kk4 + 1][r] = av.y;
            As[kk4 + 2][r] = av.z;
            As[kk4 + 3][r] = av.w;
        }
        // Load B tile (16x64): thread -> (kk = tid/16, 4 consecutive n)
        {
            int kk = tid >> 4;
            int c4 = (tid & 15) * 4;
            float4 bv = *(const float4*)&B[(size_t)(k0 + kk) * Nn + colBase + c4];
            *(float4*)&Bs[kk][c4] = bv;
        }
        __syncthreads();

#pragma unroll
        for (int kk = 0; kk < BK; ++kk) {
            float4 a = *(const float4*)&As[kk][ty * 4];
            float4 b = *(const float4*)&Bs[kk][tx * 4];
            const float av[4] = {a.x, a.y, a.z, a.w};
            const float bv[4] = {b.x, b.y, b.z, b.w};
#pragma unroll
            for (int i = 0; i < 4; ++i)
#pragma unroll
                for (int j = 0; j < 4; ++j) acc[i][j] += av[i] * bv[j];
        }
        __syncthreads();
    }

#pragma unroll
    for (int i = 0; i < 4; ++i) {
        int r = rowBase + ty * 4 + i;
#pragma unroll
        for (int j = 0; j < 4; ++j) {
            int c = colBase + tx * 4 + j;
            float v = acc[i][j] + bias[c];
            if (EPI == 1) v = 0.5f * v * (1.0f + erff(v * 0.70710678118654752f));
            if (EPI == 2) v += res[(size_t)r * Nn + c];
            C[(size_t)r * Nn + c] = v;
        }
    }
}

// ---------------------------------------------------------------------------
// Segment attention: one wave per (row, head); lane = head-dim element.
// Online softmax over the row's doc segment (mean len ~6).
// qkv layout: row-major (NP x 768); q at col [h*64], k at [256+h*64],
// v at [512+h*64]. attn_out: (NP x 256), col = h*64 + d.
// ---------------------------------------------------------------------------
__global__ __launch_bounds__(256) void attn_kernel(
    const float* __restrict__ qkv, const int* __restrict__ seg_s,
    const int* __restrict__ seg_e, float* __restrict__ attn_out) {
    int wid = blockIdx.x * 4 + (threadIdx.x >> 6);
    int lane = threadIdx.x & 63;
    int row = wid >> 2;
    int h = wid & 3;
    if (row >= NP) return;

    const float qd = qkv[(size_t)row * 768 + h * 64 + lane];
    const int s = seg_s[row], e = seg_e[row];

    float m = -INFINITY, l = 0.0f, acc = 0.0f;
    for (int j = s; j < e; ++j) {
        const float* kr = qkv + (size_t)j * 768 + 256 + h * 64;
        float prod = qd * kr[lane];
#pragma unroll
        for (int off = 32; off; off >>= 1) prod += __shfl_xor(prod, off);
        float score = prod * 0.125f;  // 1/sqrt(64)
        float mn = fmaxf(m, score);
        float scale = __expf(m - mn);    // first iter: exp(-inf)=0
        float p = __expf(score - mn);
        l = l * scale + p;
        acc = acc * scale + p * qkv[(size_t)j * 768 + 512 + h * 64 + lane];
        m = mn;
    }
    attn_out[(size_t)row * 256 + h * 64 + lane] = acc / l;
}

// ---------------------------------------------------------------------------
// LayerNorm over rows of 256: one wave per row, lane holds 4 contiguous f32.
// ---------------------------------------------------------------------------
__global__ __launch_bounds__(256) void ln_kernel(
    const float* __restrict__ in, const float* __restrict__ g,
    const float* __restrict__ b, float* __restrict__ out) {
    int wid = blockIdx.x * 4 + (threadIdx.x >> 6);
    int lane = threadIdx.x & 63;
    if (wid >= NP) return;

    float4 v = ((const float4*)(in + (size_t)wid * 256))[lane];
    float s = v.x + v.y + v.z + v.w;
#pragma unroll
    for (int off = 32; off; off >>= 1) s += __shfl_xor(s, off);
    float mu = s * (1.0f / 256.0f);
    float dx = v.x - mu, dy = v.y - mu, dz = v.z - mu, dw = v.w - mu;
    float ss = dx * dx + dy * dy + dz * dz + dw * dw;
#pragma unroll
    for (int off = 32; off; off >>= 1) ss += __shfl_xor(ss, off);
    float rstd = rsqrtf(ss * (1.0f / 256.0f) + LNEPS);

    float4 gg = ((const float4*)g)[lane];
    float4 bb = ((const float4*)b)[lane];
    float4 o;
    o.x = dx * rstd * gg.x + bb.x;
    o.y = dy * rstd * gg.y + bb.y;
    o.z = dz * rstd * gg.z + bb.z;
    o.w = dw * rstd * gg.w + bb.w;
    ((float4*)(out + (size_t)wid * 256))[lane] = o;
}

// ---------------------------------------------------------------------------
extern "C" void kernel_launch(void* const* d_in, const int* in_sizes, int n_in,
                              void* d_out, int out_size, void* d_ws, size_t ws_size,
                              hipStream_t stream) {
    const float* x      = (const float*)d_in[0];
    const int*   dom    = (const int*)d_in[1];
    const float* qkv_w  = (const float*)d_in[2];
    const float* qkv_b  = (const float*)d_in[3];
    const float* out_w  = (const float*)d_in[4];
    const float* out_b  = (const float*)d_in[5];
    const float* ff_w1  = (const float*)d_in[6];
    const float* ff_b1  = (const float*)d_in[7];
    const float* ff_w2  = (const float*)d_in[8];
    const float* ff_b2  = (const float*)d_in[9];
    const float* ln1_g  = (const float*)d_in[10];
    const float* ln1_b  = (const float*)d_in[11];
    const float* ln2_g  = (const float*)d_in[12];
    const float* ln2_b  = (const float*)d_in[13];
    float* out = (float*)d_out;

    // Workspace layout (floats). bufA holds qkv (NP*768) then is reused for
    // the ff hidden h (NP*1024) once qkv is dead (after attention).
    float* bufA   = (float*)d_ws;                 // max(NP*768, NP*1024)
    float* attn_o = bufA + (size_t)NP * DFF;      // NP*256
    float* y      = attn_o + (size_t)NP * DM;     // NP*256 (y1 then y2)
    float* x1     = y + (size_t)NP * DM;          // NP*256
    int* seg_s    = (int*)(x1 + (size_t)NP * DM);
    int* seg_e    = seg_s + NP;

    float* qkv = bufA;
    float* h   = bufA;

    // 1) segment bounds
    seg_kernel<<<(NP + 255) / 256, 256, 0, stream>>>(dom, seg_s, seg_e);

    // 2) qkv = x @ qkv_w + qkv_b          (6144 x 768, K=256)
    gemm_kernel<0><<<dim3(768 / BN, NP / BM), 256, 0, stream>>>(
        x, qkv_w, qkv_b, nullptr, qkv, NP, 768, DM);

    // 3) segment attention -> attn_o      (6144 x 256)
    attn_kernel<<<NP, 256, 0, stream>>>(qkv, seg_s, seg_e, attn_o);

    // 4) y = x + attn_o @ out_w + out_b   (6144 x 256, K=256)
    gemm_kernel<2><<<dim3(DM / BN, NP / BM), 256, 0, stream>>>(
        attn_o, out_w, out_b, x, y, NP, DM, DM);

    // 5) x1 = LN1(y)
    ln_kernel<<<NP / 4, 256, 0, stream>>>(y, ln1_g, ln1_b, x1);

    // 6) h = gelu(x1 @ ff_w1 + ff_b1)     (6144 x 1024, K=256)
    gemm_kernel<1><<<dim3(DFF / BN, NP / BM), 256, 0, stream>>>(
        x1, ff_w1, ff_b1, nullptr, h, NP, DFF, DM);

    // 7) y = x1 + h @ ff_w2 + ff_b2       (6144 x 256, K=1024)
    gemm_kernel<2><<<dim3(DM / BN, NP / BM), 256, 0, stream>>>(
        h, ff_w2, ff_b2, x1, y, NP, DM, DFF);

    // 8) out = LN2(y)
    ln_kernel<<<NP / 4, 256, 0, stream>>>(y, ln2_g, ln2_b, out);
}

// Round 2
// 112.001 us; speedup vs baseline: 1.9212x; 1.9212x over previous
//
#include <hip/hip_runtime.h>
#include <hip/hip_bf16.h>
#include <math.h>

// Problem constants
constexpr int NP     = 6144;   // pulses (rows)
constexpr int DM     = 256;    // d_model
constexpr int DFF    = 1024;   // ff dim
constexpr float LNEPS = 1e-5f;

typedef __attribute__((ext_vector_type(8))) short short8;
typedef __attribute__((ext_vector_type(4))) short short4v;
typedef __attribute__((ext_vector_type(4))) float f32x4;

__device__ __forceinline__ short f2bf(float f) {
    unsigned u = __builtin_bit_cast(unsigned, f);
    unsigned r = u + 0x7FFFu + ((u >> 16) & 1u);   // RNE
    return (short)(r >> 16);
}

// ---------------------------------------------------------------------------
// Segment bounds: pulse_to_dom_idx is sorted -> same-doc rows contiguous.
// ---------------------------------------------------------------------------
__global__ void seg_kernel(const int* __restrict__ idx,
                           int* __restrict__ seg_s, int* __restrict__ seg_e) {
    int i = blockIdx.x * blockDim.x + threadIdx.x;
    if (i >= NP) return;
    int d = idx[i];
    int s = i;
    while (s > 0 && idx[s - 1] == d) --s;
    int e = i + 1;
    while (e < NP && idx[e] == d) ++e;
    seg_s[i] = s;
    seg_e[i] = e;
}

// ---------------------------------------------------------------------------
// Weight prep: convert fp32 [K][N] -> bf16 [N][K] (K-contiguous) for all 4
// weight matrices. One block per 32x32 tile; LDS transpose.
// Tile counts: qkv 8*24=192, out 8*8=64, ff1 8*32=256, ff2 32*8=256 -> 768.
// ---------------------------------------------------------------------------
__global__ __launch_bounds__(256) void wprep_kernel(
    const float* __restrict__ qkv_w, const float* __restrict__ out_w,
    const float* __restrict__ ff_w1, const float* __restrict__ ff_w2,
    short* __restrict__ qkvT, short* __restrict__ outT,
    short* __restrict__ ff1T, short* __restrict__ ff2T) {
    int b = blockIdx.x;
    const float* src;
    short* dst;
    int K, Nn;
    if (b < 192)      { src = qkv_w; dst = qkvT; K = 256;  Nn = 768; }
    else if (b < 256) { b -= 192; src = out_w; dst = outT; K = 256;  Nn = 256; }
    else if (b < 512) { b -= 256; src = ff_w1; dst = ff1T; K = 256;  Nn = 1024; }
    else              { b -= 512; src = ff_w2; dst = ff2T; K = 1024; Nn = 256; }
    int tpr = Nn / 32;
    int k0 = (b / tpr) * 32, n0 = (b % tpr) * 32;

    __shared__ float lds[32][36];
    int t = threadIdx.x;
    {
        int k = t >> 3, n = (t & 7) * 4;
        *(float4*)&lds[k][n] = *(const float4*)&src[(size_t)(k0 + k) * Nn + n0 + n];
    }
    __syncthreads();
    {
        int n = t >> 3, ks = (t & 7) * 4;
        short4v o = { f2bf(lds[ks + 0][n]), f2bf(lds[ks + 1][n]),
                      f2bf(lds[ks + 2][n]), f2bf(lds[ks + 3][n]) };
        *(short4v*)&dst[(size_t)(n0 + n) * K + k0 + ks] = o;
    }
}

// ---------------------------------------------------------------------------
// MFMA GEMM: C[M,N] = A[M,K](fp32) @ Bt[N,K](bf16)^T + bias, epilogue EPI:
// 0 = none, 1 = exact GELU, 2 = += residual.
// Tile 64x64, BK=64, 256 threads = 4 waves (2x2), each wave 32x32 via
// 2x2 fragments of mfma_f32_16x16x32_bf16. fp32 accumulate.
// ---------------------------------------------------------------------------
constexpr int BM = 64, BN = 64, BK = 64;
constexpr int LDK = BK + 8;   // shorts per LDS row (144 B, 16B-aligned)

template <int EPI>
__global__ __launch_bounds__(256) void mgemm(
    const float* __restrict__ A, const short* __restrict__ Bt,
    const float* __restrict__ bias, const float* __restrict__ res,
    float* __restrict__ C, int M, int Nn, int K) {
    __shared__ __align__(16) short As[BM * LDK];
    __shared__ __align__(16) short Bs[BN * LDK];

    const int tid  = threadIdx.x;
    const int lane = tid & 63;
    const int w    = tid >> 6;
    const int wm   = (w >> 1) * 32, wn = (w & 1) * 32;
    const int rowBase = blockIdx.y * BM;
    const int colBase = blockIdx.x * BN;

    const int sr = tid >> 2;          // staging row 0..63
    const int sk = (tid & 3) * 16;    // staging k offset 0,16,32,48

    f32x4 acc[2][2];
#pragma unroll
    for (int i = 0; i < 2; ++i)
#pragma unroll
        for (int j = 0; j < 2; ++j) acc[i][j] = f32x4{0.f, 0.f, 0.f, 0.f};

    for (int k0 = 0; k0 < K; k0 += BK) {
        // Stage A (fp32 -> bf16): row sr, 16 consecutive k
        {
            const float* ap = A + (size_t)(rowBase + sr) * K + k0 + sk;
            float4 a0 = *(const float4*)(ap + 0);
            float4 a1 = *(const float4*)(ap + 4);
            float4 a2 = *(const float4*)(ap + 8);
            float4 a3 = *(const float4*)(ap + 12);
            short8 v0 = { f2bf(a0.x), f2bf(a0.y), f2bf(a0.z), f2bf(a0.w),
                          f2bf(a1.x), f2bf(a1.y), f2bf(a1.z), f2bf(a1.w) };
            short8 v1 = { f2bf(a2.x), f2bf(a2.y), f2bf(a2.z), f2bf(a2.w),
                          f2bf(a3.x), f2bf(a3.y), f2bf(a3.z), f2bf(a3.w) };
            *(short8*)&As[sr * LDK + sk + 0] = v0;
            *(short8*)&As[sr * LDK + sk + 8] = v1;
        }
        // Stage Bt (already bf16, K-contiguous): row = n, 16 consecutive k
        {
            const short* bp = Bt + (size_t)(colBase + sr) * K + k0 + sk;
            short8 b0 = *(const short8*)(bp + 0);
            short8 b1 = *(const short8*)(bp + 8);
            *(short8*)&Bs[sr * LDK + sk + 0] = b0;
            *(short8*)&Bs[sr * LDK + sk + 8] = b1;
        }
        __syncthreads();

#pragma unroll
        for (int kk = 0; kk < BK; kk += 32) {
            const int kb = kk + (lane >> 4) * 8;
            const int fr = lane & 15;
            short8 af[2], bf[2];
            af[0] = *(const short8*)&As[(wm + 0  + fr) * LDK + kb];
            af[1] = *(const short8*)&As[(wm + 16 + fr) * LDK + kb];
            bf[0] = *(const short8*)&Bs[(wn + 0  + fr) * LDK + kb];
            bf[1] = *(const short8*)&Bs[(wn + 16 + fr) * LDK + kb];
#pragma unroll
            for (int fm = 0; fm < 2; ++fm)
#pragma unroll
                for (int fn = 0; fn < 2; ++fn)
                    acc[fm][fn] = __builtin_amdgcn_mfma_f32_16x16x32_bf16(
                        af[fm], bf[fn], acc[fm][fn], 0, 0, 0);
        }
        __syncthreads();
    }

    // Epilogue. C/D layout: col = lane&15, row = (lane>>4)*4 + reg.
    const int cc = lane & 15;
    const int cr = (lane >> 4) * 4;
#pragma unroll
    for (int fm = 0; fm < 2; ++fm)
#pragma unroll
        for (int fn = 0; fn < 2; ++fn) {
            int c = colBase + wn + fn * 16 + cc;
            float bv = bias[c];
#pragma unroll
            for (int j = 0; j < 4; ++j) {
                int r = rowBase + wm + fm * 16 + cr + j;
                float v = acc[fm][fn][j] + bv;
                if (EPI == 1) v = 0.5f * v * (1.0f + erff(v * 0.70710678118654752f));
                if (EPI == 2) v += res[(size_t)r * Nn + c];
                C[(size_t)r * Nn + c] = v;
            }
        }
}

// ---------------------------------------------------------------------------
// Segment attention: one wave per (row, head); lane = head-dim element.
// ---------------------------------------------------------------------------
__global__ __launch_bounds__(256) void attn_kernel(
    const float* __restrict__ qkv, const int* __restrict__ seg_s,
    const int* __restrict__ seg_e, float* __restrict__ attn_out) {
    int wid = blockIdx.x * 4 + (threadIdx.x >> 6);
    int lane = threadIdx.x & 63;
    int row = wid >> 2;
    int h = wid & 3;
    if (row >= NP) return;

    const float qd = qkv[(size_t)row * 768 + h * 64 + lane];
    const int s = seg_s[row], e = seg_e[row];

    float m = -INFINITY, l = 0.0f, acc = 0.0f;
    for (int j = s; j < e; ++j) {
        const float* kr = qkv + (size_t)j * 768 + 256 + h * 64;
        float prod = qd * kr[lane];
#pragma unroll
        for (int off = 32; off; off >>= 1) prod += __shfl_xor(prod, off);
        float score = prod * 0.125f;  // 1/sqrt(64)
        float mn = fmaxf(m, score);
        float scale = __expf(m - mn);
        float p = __expf(score - mn);
        l = l * scale + p;
        acc = acc * scale + p * qkv[(size_t)j * 768 + 512 + h * 64 + lane];
        m = mn;
    }
    attn_out[(size_t)row * 256 + h * 64 + lane] = acc / l;
}

// ---------------------------------------------------------------------------
// LayerNorm over rows of 256: one wave per row.
// ---------------------------------------------------------------------------
__global__ __launch_bounds__(256) void ln_kernel(
    const float* __restrict__ in, const float* __restrict__ g,
    const float* __restrict__ b, float* __restrict__ out) {
    int wid = blockIdx.x * 4 + (threadIdx.x >> 6);
    int lane = threadIdx.x & 63;
    if (wid >= NP) return;

    float4 v = ((const float4*)(in + (size_t)wid * 256))[lane];
    float s = v.x + v.y + v.z + v.w;
#pragma unroll
    for (int off = 32; off; off >>= 1) s += __shfl_xor(s, off);
    float mu = s * (1.0f / 256.0f);
    float dx = v.x - mu, dy = v.y - mu, dz = v.z - mu, dw = v.w - mu;
    float ss = dx * dx + dy * dy + dz * dz + dw * dw;
#pragma unroll
    for (int off = 32; off; off >>= 1) ss += __shfl_xor(ss, off);
    float rstd = rsqrtf(ss * (1.0f / 256.0f) + LNEPS);

    float4 gg = ((const float4*)g)[lane];
    float4 bb = ((const float4*)b)[lane];
    float4 o;
    o.x = dx * rstd * gg.x + bb.x;
    o.y = dy * rstd * gg.y + bb.y;
    o.z = dz * rstd * gg.z + bb.z;
    o.w = dw * rstd * gg.w + bb.w;
    ((float4*)(out + (size_t)wid * 256))[lane] = o;
}

// ---------------------------------------------------------------------------
extern "C" void kernel_launch(void* const* d_in, const int* in_sizes, int n_in,
                              void* d_out, int out_size, void* d_ws, size_t ws_size,
                              hipStream_t stream) {
    const float* x      = (const float*)d_in[0];
    const int*   dom    = (const int*)d_in[1];
    const float* qkv_w  = (const float*)d_in[2];
    const float* qkv_b  = (const float*)d_in[3];
    const float* out_w  = (const float*)d_in[4];
    const float* out_b  = (const float*)d_in[5];
    const float* ff_w1  = (const float*)d_in[6];
    const float* ff_b1  = (const float*)d_in[7];
    const float* ff_w2  = (const float*)d_in[8];
    const float* ff_b2  = (const float*)d_in[9];
    const float* ln1_g  = (const float*)d_in[10];
    const float* ln1_b  = (const float*)d_in[11];
    const float* ln2_g  = (const float*)d_in[12];
    const float* ln2_b  = (const float*)d_in[13];
    float* out = (float*)d_out;

    // Workspace layout (NOTE: attn_o aliases bufA's tail beyond qkv's 768
    // cols; qkv is dead once attention has run, h overwrites bufA later).
    float* bufA   = (float*)d_ws;                    // NP*1024 floats
    float* attn_o = bufA + (size_t)NP * 768;         // NP*256 (alias tail)
    float* y      = bufA + (size_t)NP * DFF;         // NP*256
    float* x1     = y + (size_t)NP * DM;             // NP*256
    short* wT     = (short*)(x1 + (size_t)NP * DM);  // bf16 transposed weights
    short* qkvT   = wT;                              // 768*256
    short* outT   = qkvT + 768 * 256;                // 256*256
    short* ff1T   = outT + 256 * 256;                // 1024*256
    short* ff2T   = ff1T + 1024 * 256;               // 256*1024
    int* seg_s    = (int*)(ff2T + 256 * 1024);
    int* seg_e    = seg_s + NP;

    float* qkv = bufA;
    float* h   = bufA;

    // 0) weight transpose+convert, segment bounds (independent)
    wprep_kernel<<<768, 256, 0, stream>>>(qkv_w, out_w, ff_w1, ff_w2,
                                          qkvT, outT, ff1T, ff2T);
    seg_kernel<<<(NP + 255) / 256, 256, 0, stream>>>(dom, seg_s, seg_e);

    // 1) qkv = x @ qkv_w + qkv_b          (6144 x 768, K=256)
    mgemm<0><<<dim3(768 / BN, NP / BM), 256, 0, stream>>>(
        x, qkvT, qkv_b, nullptr, qkv, NP, 768, DM);

    // 2) segment attention -> attn_o
    attn_kernel<<<NP, 256, 0, stream>>>(qkv, seg_s, seg_e, attn_o);

    // 3) y = x + attn_o @ out_w + out_b   (6144 x 256, K=256)
    mgemm<2><<<dim3(DM / BN, NP / BM), 256, 0, stream>>>(
        attn_o, outT, out_b, x, y, NP, DM, DM);

    // 4) x1 = LN1(y)
    ln_kernel<<<NP / 4, 256, 0, stream>>>(y, ln1_g, ln1_b, x1);

    // 5) h = gelu(x1 @ ff_w1 + ff_b1)     (6144 x 1024, K=256)
    mgemm<1><<<dim3(DFF / BN, NP / BM), 256, 0, stream>>>(
        x1, ff1T, ff_b1, nullptr, h, NP, DFF, DM);

    // 6) y = x1 + h @ ff_w2 + ff_b2       (6144 x 256, K=1024)
    mgemm<2><<<dim3(DM / BN, NP / BM), 256, 0, stream>>>(
        h, ff2T, ff_b2, x1, y, NP, DM, DFF);

    // 7) out = LN2(y)
    ln_kernel<<<NP / 4, 256, 0, stream>>>(y, ln2_g, ln2_b, out);
}

// Round 3
// 84.636 us; speedup vs baseline: 2.5423x; 1.3233x over previous
//
#include <hip/hip_runtime.h>
#include <hip/hip_bf16.h>
#include <math.h>

constexpr int NP  = 6144;   // rows
constexpr int DM  = 256;    // d_model
constexpr int DFF = 1024;   // ff dim
constexpr float LNEPS = 1e-5f;

typedef __attribute__((ext_vector_type(8))) short short8;
typedef __attribute__((ext_vector_type(4))) short short4v;
typedef __attribute__((ext_vector_type(4))) float f32x4;

__device__ __forceinline__ short f2bf(float f) {
    unsigned u = __builtin_bit_cast(unsigned, f);
    unsigned r = u + 0x7FFFu + ((u >> 16) & 1u);   // RNE
    return (short)(r >> 16);
}
__device__ __forceinline__ float bf2f(short s) {
    unsigned u = ((unsigned)(unsigned short)s) << 16;
    return __builtin_bit_cast(float, u);
}

// ---------------------------------------------------------------------------
// prep: blocks 0..767 transpose+convert the 4 weight mats fp32[K][N] ->
// bf16[N][K]; blocks 768..791 compute segment bounds (sorted doc ids).
// ---------------------------------------------------------------------------
__global__ __launch_bounds__(256) void prep_kernel(
    const float* __restrict__ qkv_w, const float* __restrict__ out_w,
    const float* __restrict__ ff_w1, const float* __restrict__ ff_w2,
    short* __restrict__ qkvT, short* __restrict__ outT,
    short* __restrict__ ff1T, short* __restrict__ ff2T,
    const int* __restrict__ dom, int* __restrict__ seg_s,
    int* __restrict__ seg_e) {
    int b = blockIdx.x;
    if (b >= 768) {
        int i = (b - 768) * 256 + threadIdx.x;
        if (i >= NP) return;
        int d = dom[i];
        int s = i;
        while (s > 0 && dom[s - 1] == d) --s;
        int e = i + 1;
        while (e < NP && dom[e] == d) ++e;
        seg_s[i] = s;
        seg_e[i] = e;
        return;
    }
    const float* src;
    short* dst;
    int K, Nn;
    if (b < 192)      { src = qkv_w; dst = qkvT; K = 256;  Nn = 768; }
    else if (b < 256) { b -= 192; src = out_w; dst = outT; K = 256;  Nn = 256; }
    else if (b < 512) { b -= 256; src = ff_w1; dst = ff1T; K = 256;  Nn = 1024; }
    else              { b -= 512; src = ff_w2; dst = ff2T; K = 1024; Nn = 256; }
    int tpr = Nn / 32;
    int k0 = (b / tpr) * 32, n0 = (b % tpr) * 32;

    __shared__ float lds[32][36];
    int t = threadIdx.x;
    {
        int k = t >> 3, n = (t & 7) * 4;
        *(float4*)&lds[k][n] = *(const float4*)&src[(size_t)(k0 + k) * Nn + n0 + n];
    }
    __syncthreads();
    {
        int n = t >> 3, ks = (t & 7) * 4;
        short4v o = { f2bf(lds[ks + 0][n]), f2bf(lds[ks + 1][n]),
                      f2bf(lds[ks + 2][n]), f2bf(lds[ks + 3][n]) };
        *(short4v*)&dst[(size_t)(n0 + n) * K + k0 + ks] = o;
    }
}

// ---------------------------------------------------------------------------
// mgemm64: C_bf16[M,Nn] = A[M,K] @ Bt[Nn,K]^T + bias (opt GELU).
// A fp32 (converted during staging) or bf16. Tile 64x64, BK=64, 4 waves,
// each wave 32x32 via 2x2 frags of mfma_f32_16x16x32_bf16.
// ---------------------------------------------------------------------------
template <bool ABF, bool GELU>
__global__ __launch_bounds__(256) void mgemm64(
    const void* __restrict__ Av, const short* __restrict__ Bt,
    const float* __restrict__ bias, short* __restrict__ C, int Nn, int K) {
    __shared__ __align__(16) short As[64 * 72];
    __shared__ __align__(16) short Bs[64 * 72];

    const int tid = threadIdx.x, lane = tid & 63, w = tid >> 6;
    const int wm = (w >> 1) * 32, wn = (w & 1) * 32;
    const int rowBase = blockIdx.y * 64, colBase = blockIdx.x * 64;
    const int sr = tid >> 2, sk = (tid & 3) * 16;

    f32x4 acc[2][2];
#pragma unroll
    for (int i = 0; i < 2; ++i)
#pragma unroll
        for (int j = 0; j < 2; ++j) acc[i][j] = f32x4{0.f, 0.f, 0.f, 0.f};

    for (int k0 = 0; k0 < K; k0 += 64) {
        if (ABF) {
            const short* ap = (const short*)Av + (size_t)(rowBase + sr) * K + k0 + sk;
            *(short8*)&As[sr * 72 + sk + 0] = *(const short8*)(ap + 0);
            *(short8*)&As[sr * 72 + sk + 8] = *(const short8*)(ap + 8);
        } else {
            const float* ap = (const float*)Av + (size_t)(rowBase + sr) * K + k0 + sk;
            float4 a0 = *(const float4*)(ap + 0);
            float4 a1 = *(const float4*)(ap + 4);
            float4 a2 = *(const float4*)(ap + 8);
            float4 a3 = *(const float4*)(ap + 12);
            short8 v0 = { f2bf(a0.x), f2bf(a0.y), f2bf(a0.z), f2bf(a0.w),
                          f2bf(a1.x), f2bf(a1.y), f2bf(a1.z), f2bf(a1.w) };
            short8 v1 = { f2bf(a2.x), f2bf(a2.y), f2bf(a2.z), f2bf(a2.w),
                          f2bf(a3.x), f2bf(a3.y), f2bf(a3.z), f2bf(a3.w) };
            *(short8*)&As[sr * 72 + sk + 0] = v0;
            *(short8*)&As[sr * 72 + sk + 8] = v1;
        }
        {
            const short* bp = Bt + (size_t)(colBase + sr) * K + k0 + sk;
            *(short8*)&Bs[sr * 72 + sk + 0] = *(const short8*)(bp + 0);
            *(short8*)&Bs[sr * 72 + sk + 8] = *(const short8*)(bp + 8);
        }
        __syncthreads();

#pragma unroll
        for (int kk = 0; kk < 64; kk += 32) {
            const int kb = kk + (lane >> 4) * 8;
            const int fr = lane & 15;
            short8 af[2], bfv[2];
            af[0]  = *(const short8*)&As[(wm + 0  + fr) * 72 + kb];
            af[1]  = *(const short8*)&As[(wm + 16 + fr) * 72 + kb];
            bfv[0] = *(const short8*)&Bs[(wn + 0  + fr) * 72 + kb];
            bfv[1] = *(const short8*)&Bs[(wn + 16 + fr) * 72 + kb];
#pragma unroll
            for (int fm = 0; fm < 2; ++fm)
#pragma unroll
                for (int fn = 0; fn < 2; ++fn)
                    acc[fm][fn] = __builtin_amdgcn_mfma_f32_16x16x32_bf16(
                        af[fm], bfv[fn], acc[fm][fn], 0, 0, 0);
        }
        __syncthreads();
    }

    const int cc = lane & 15, cr = (lane >> 4) * 4;
#pragma unroll
    for (int fm = 0; fm < 2; ++fm)
#pragma unroll
        for (int fn = 0; fn < 2; ++fn) {
            int c = colBase + wn + fn * 16 + cc;
            float bv = bias[c];
#pragma unroll
            for (int j = 0; j < 4; ++j) {
                int r = rowBase + wm + fm * 16 + cr + j;
                float v = acc[fm][fn][j] + bv;
                if (GELU) v = 0.5f * v * (1.0f + erff(v * 0.70710678118654752f));
                C[(size_t)r * Nn + c] = f2bf(v);
            }
        }
}

// ---------------------------------------------------------------------------
// gemmln: fused C = LN( A @ Bt^T + bias + res ) for Nn == 256 (full rows in
// block). Tile 32x256, BK=64, 4 waves; wave w owns cols [w*64, w*64+64),
// all 32 rows: acc[2(fm)][4(fn)]. Row stats via shfl + LDS cross-wave sum.
// ---------------------------------------------------------------------------
template <bool RESBF, bool OUTBF>
__global__ __launch_bounds__(256) void gemmln(
    const short* __restrict__ A, const short* __restrict__ Bt,
    const float* __restrict__ bias, const void* __restrict__ resv,
    const float* __restrict__ gw, const float* __restrict__ bw,
    void* __restrict__ Cv, int K) {
    __shared__ __align__(16) short As[32 * 72];
    __shared__ __align__(16) short Bs[256 * 72];
    __shared__ float red1[4][32], red2[4][32];

    const int tid = threadIdx.x, lane = tid & 63, w = tid >> 6;
    const int rowBase = blockIdx.x * 32;
    const int cc = lane & 15, g4 = lane >> 4;

    f32x4 acc[2][4];
#pragma unroll
    for (int i = 0; i < 2; ++i)
#pragma unroll
        for (int j = 0; j < 4; ++j) acc[i][j] = f32x4{0.f, 0.f, 0.f, 0.f};

    const int ar = tid >> 3, ak = (tid & 7) * 8;

    for (int k0 = 0; k0 < K; k0 += 64) {
        *(short8*)&As[ar * 72 + ak] =
            *(const short8*)(A + (size_t)(rowBase + ar) * K + k0 + ak);
#pragma unroll
        for (int i = 0; i < 8; ++i) {
            int idx = i * 256 + tid;
            int br = idx >> 3, bk = (idx & 7) * 8;
            *(short8*)&Bs[br * 72 + bk] =
                *(const short8*)(Bt + (size_t)br * K + k0 + bk);
        }
        __syncthreads();

#pragma unroll
        for (int kk = 0; kk < 64; kk += 32) {
            const int kb = kk + g4 * 8;
            short8 af[2], bfv[4];
            af[0] = *(const short8*)&As[(0  + cc) * 72 + kb];
            af[1] = *(const short8*)&As[(16 + cc) * 72 + kb];
#pragma unroll
            for (int fn = 0; fn < 4; ++fn)
                bfv[fn] = *(const short8*)&Bs[(w * 64 + fn * 16 + cc) * 72 + kb];
#pragma unroll
            for (int fm = 0; fm < 2; ++fm)
#pragma unroll
                for (int fn = 0; fn < 4; ++fn)
                    acc[fm][fn] = __builtin_amdgcn_mfma_f32_16x16x32_bf16(
                        af[fm], bfv[fn], acc[fm][fn], 0, 0, 0);
        }
        __syncthreads();
    }

    // epilogue: bias + residual, then row LN over 256 cols
    float v[2][4][4];
    float p1[2][4], p2[2][4];
#pragma unroll
    for (int fm = 0; fm < 2; ++fm)
#pragma unroll
        for (int j = 0; j < 4; ++j) { p1[fm][j] = 0.f; p2[fm][j] = 0.f; }

#pragma unroll
    for (int fm = 0; fm < 2; ++fm)
#pragma unroll
        for (int fn = 0; fn < 4; ++fn) {
            int c = w * 64 + fn * 16 + cc;
            float bv = bias[c];
#pragma unroll
            for (int j = 0; j < 4; ++j) {
                int r = rowBase + fm * 16 + g4 * 4 + j;
                float t = acc[fm][fn][j] + bv;
                if (RESBF) t += bf2f(((const short*)resv)[(size_t)r * 256 + c]);
                else       t += ((const float*)resv)[(size_t)r * 256 + c];
                v[fm][fn][j] = t;
                p1[fm][j] += t;
                p2[fm][j] += t * t;
            }
        }

#pragma unroll
    for (int m = 1; m < 16; m <<= 1) {
#pragma unroll
        for (int fm = 0; fm < 2; ++fm)
#pragma unroll
            for (int j = 0; j < 4; ++j) {
                p1[fm][j] += __shfl_xor(p1[fm][j], m);
                p2[fm][j] += __shfl_xor(p2[fm][j], m);
            }
    }
    if (cc == 0) {
#pragma unroll
        for (int fm = 0; fm < 2; ++fm)
#pragma unroll
            for (int j = 0; j < 4; ++j) {
                red1[w][fm * 16 + g4 * 4 + j] = p1[fm][j];
                red2[w][fm * 16 + g4 * 4 + j] = p2[fm][j];
            }
    }
    __syncthreads();

#pragma unroll
    for (int fm = 0; fm < 2; ++fm)
#pragma unroll
        for (int j = 0; j < 4; ++j) {
            int rl = fm * 16 + g4 * 4 + j;
            int r = rowBase + rl;
            float s1 = red1[0][rl] + red1[1][rl] + red1[2][rl] + red1[3][rl];
            float s2 = red2[0][rl] + red2[1][rl] + red2[2][rl] + red2[3][rl];
            float mu = s1 * (1.0f / 256.0f);
            float var = s2 * (1.0f / 256.0f) - mu * mu;
            float rstd = rsqrtf(var + LNEPS);
#pragma unroll
            for (int fn = 0; fn < 4; ++fn) {
                int c = w * 64 + fn * 16 + cc;
                float o = (v[fm][fn][j] - mu) * rstd * gw[c] + bw[c];
                if (OUTBF) ((short*)Cv)[(size_t)r * 256 + c] = f2bf(o);
                else       ((float*)Cv)[(size_t)r * 256 + c] = o;
            }
        }
}

// ---------------------------------------------------------------------------
// Segment attention on bf16 qkv: one wave per (row, head).
// ---------------------------------------------------------------------------
__global__ __launch_bounds__(256) void attn_kernel(
    const short* __restrict__ qkv, const int* __restrict__ seg_s,
    const int* __restrict__ seg_e, short* __restrict__ attn_out) {
    int h = threadIdx.x >> 6;
    int lane = threadIdx.x & 63;
    int row = blockIdx.x;

    const float qd = bf2f(qkv[(size_t)row * 768 + h * 64 + lane]);
    const int s = seg_s[row], e = seg_e[row];

    float m = -INFINITY, l = 0.0f, acc = 0.0f;
    for (int j = s; j < e; ++j) {
        float kd = bf2f(qkv[(size_t)j * 768 + 256 + h * 64 + lane]);
        float prod = qd * kd;
#pragma unroll
        for (int off = 32; off; off >>= 1) prod += __shfl_xor(prod, off);
        float score = prod * 0.125f;   // 1/sqrt(64)
        float mn = fmaxf(m, score);
        float scale = __expf(m - mn);
        float p = __expf(score - mn);
        l = l * scale + p;
        acc = acc * scale + p * bf2f(qkv[(size_t)j * 768 + 512 + h * 64 + lane]);
        m = mn;
    }
    attn_out[(size_t)row * 256 + h * 64 + lane] = f2bf(acc / l);
}

// ---------------------------------------------------------------------------
extern "C" void kernel_launch(void* const* d_in, const int* in_sizes, int n_in,
                              void* d_out, int out_size, void* d_ws, size_t ws_size,
                              hipStream_t stream) {
    const float* x      = (const float*)d_in[0];
    const int*   dom    = (const int*)d_in[1];
    const float* qkv_w  = (const float*)d_in[2];
    const float* qkv_b  = (const float*)d_in[3];
    const float* out_w  = (const float*)d_in[4];
    const float* out_b  = (const float*)d_in[5];
    const float* ff_w1  = (const float*)d_in[6];
    const float* ff_b1  = (const float*)d_in[7];
    const float* ff_w2  = (const float*)d_in[8];
    const float* ff_b2  = (const float*)d_in[9];
    const float* ln1_g  = (const float*)d_in[10];
    const float* ln1_b  = (const float*)d_in[11];
    const float* ln2_g  = (const float*)d_in[12];
    const float* ln2_b  = (const float*)d_in[13];
    float* out = (float*)d_out;

    short* qkvB   = (short*)d_ws;                    // NP x 768
    short* attn_o = qkvB + (size_t)NP * 768;         // NP x 256
    short* x1     = attn_o + (size_t)NP * 256;       // NP x 256
    short* hB     = x1 + (size_t)NP * 256;           // NP x 1024
    short* qkvT   = hB + (size_t)NP * 1024;          // 768 x 256
    short* outT   = qkvT + 768 * 256;                // 256 x 256
    short* ff1T   = outT + 256 * 256;                // 1024 x 256
    short* ff2T   = ff1T + 1024 * 256;               // 256 x 1024
    int* seg_s    = (int*)(ff2T + 256 * 1024);
    int* seg_e    = seg_s + NP;

    // 0) weight transpose/convert + segment bounds (one launch)
    prep_kernel<<<792, 256, 0, stream>>>(qkv_w, out_w, ff_w1, ff_w2,
                                         qkvT, outT, ff1T, ff2T,
                                         dom, seg_s, seg_e);

    // 1) qkv = x @ qkv_w + qkv_b                (bf16 out)
    mgemm64<false, false><<<dim3(768 / 64, NP / 64), 256, 0, stream>>>(
        x, qkvT, qkv_b, qkvB, 768, 256);

    // 2) segment attention
    attn_kernel<<<NP, 256, 0, stream>>>(qkvB, seg_s, seg_e, attn_o);

    // 3) x1 = LN1(x + attn_o @ out_w + out_b)   (bf16 out, fp32 residual)
    gemmln<false, true><<<NP / 32, 256, 0, stream>>>(
        attn_o, outT, out_b, x, ln1_g, ln1_b, x1, 256);

    // 4) h = gelu(x1 @ ff_w1 + ff_b1)           (bf16 out)
    mgemm64<true, true><<<dim3(1024 / 64, NP / 64), 256, 0, stream>>>(
        x1, ff1T, ff_b1, hB, 1024, 256);

    // 5) out = LN2(x1 + h @ ff_w2 + ff_b2)      (fp32 out, bf16 residual)
    gemmln<true, false><<<NP / 32, 256, 0, stream>>>(
        hB, ff2T, ff_b2, x1, ln2_g, ln2_b, out, 1024);
}

// Round 4
// 82.520 us; speedup vs baseline: 2.6075x; 1.0256x over previous
//
#include <hip/hip_runtime.h>
#include <hip/hip_bf16.h>
#include <math.h>

constexpr int NP  = 6144;   // rows
constexpr int DM  = 256;    // d_model
constexpr int DFF = 1024;   // ff dim
constexpr float LNEPS = 1e-5f;

typedef __attribute__((ext_vector_type(8))) short short8;
typedef __attribute__((ext_vector_type(4))) short short4v;
typedef __attribute__((ext_vector_type(4))) float f32x4;

__device__ __forceinline__ short f2bf(float f) {
    unsigned u = __builtin_bit_cast(unsigned, f);
    unsigned r = u + 0x7FFFu + ((u >> 16) & 1u);   // RNE
    return (short)(r >> 16);
}
__device__ __forceinline__ float bf2f(short s) {
    unsigned u = ((unsigned)(unsigned short)s) << 16;
    return __builtin_bit_cast(float, u);
}

// global->LDS direct 16B copy. Dest is wave-uniform base + lane*16 (HW rule);
// per-lane global src carries the swizzle (guide rule #21).
#define GLOAD16(gp, lp)                                                        \
    __builtin_amdgcn_global_load_lds(                                          \
        (const __attribute__((address_space(1))) unsigned int*)(gp),           \
        (__attribute__((address_space(3))) unsigned int*)(lp), 16, 0, 0)

// LDS tile addressing: linear [rows][64] shorts (128B/row = 8 x 16B chunks),
// chunk c of row r holds global chunk c ^ (r&7). Returns short index.
__device__ __forceinline__ int lds_idx(int row, int chunk) {
    return row * 64 + ((chunk ^ (row & 7)) * 8);
}

// ---------------------------------------------------------------------------
// prep: blocks 0..767 transpose+convert weights fp32[K][N] -> bf16[N][K];
// blocks 768..791 segment bounds; blocks 792..1559 convert x -> bf16.
// ---------------------------------------------------------------------------
__global__ __launch_bounds__(256) void prep_kernel(
    const float* __restrict__ qkv_w, const float* __restrict__ out_w,
    const float* __restrict__ ff_w1, const float* __restrict__ ff_w2,
    short* __restrict__ qkvT, short* __restrict__ outT,
    short* __restrict__ ff1T, short* __restrict__ ff2T,
    const int* __restrict__ dom, int* __restrict__ seg_s,
    int* __restrict__ seg_e, const float* __restrict__ x,
    short* __restrict__ xB) {
    int b = blockIdx.x;
    if (b >= 792) {   // x -> bf16
        int i = (b - 792) * 2048 + threadIdx.x * 8;
        float4 a0 = *(const float4*)&x[i];
        float4 a1 = *(const float4*)&x[i + 4];
        short8 v = { f2bf(a0.x), f2bf(a0.y), f2bf(a0.z), f2bf(a0.w),
                     f2bf(a1.x), f2bf(a1.y), f2bf(a1.z), f2bf(a1.w) };
        *(short8*)&xB[i] = v;
        return;
    }
    if (b >= 768) {   // segment bounds
        int i = (b - 768) * 256 + threadIdx.x;
        if (i >= NP) return;
        int d = dom[i];
        int s = i;
        while (s > 0 && dom[s - 1] == d) --s;
        int e = i + 1;
        while (e < NP && dom[e] == d) ++e;
        seg_s[i] = s;
        seg_e[i] = e;
        return;
    }
    const float* src;
    short* dst;
    int K, Nn;
    if (b < 192)      { src = qkv_w; dst = qkvT; K = 256;  Nn = 768; }
    else if (b < 256) { b -= 192; src = out_w; dst = outT; K = 256;  Nn = 256; }
    else if (b < 512) { b -= 256; src = ff_w1; dst = ff1T; K = 256;  Nn = 1024; }
    else              { b -= 512; src = ff_w2; dst = ff2T; K = 1024; Nn = 256; }
    int tpr = Nn / 32;
    int k0 = (b / tpr) * 32, n0 = (b % tpr) * 32;

    __shared__ float lds[32][36];
    int t = threadIdx.x;
    {
        int k = t >> 3, n = (t & 7) * 4;
        *(float4*)&lds[k][n] = *(const float4*)&src[(size_t)(k0 + k) * Nn + n0 + n];
    }
    __syncthreads();
    {
        int n = t >> 3, ks = (t & 7) * 4;
        short4v o = { f2bf(lds[ks + 0][n]), f2bf(lds[ks + 1][n]),
                      f2bf(lds[ks + 2][n]), f2bf(lds[ks + 3][n]) };
        *(short4v*)&dst[(size_t)(n0 + n) * K + k0 + ks] = o;
    }
}

// ---------------------------------------------------------------------------
// mgemm128: C_bf16[M,Nn] = A_bf16[M,K] @ Bt_bf16[Nn,K]^T + bias (opt GELU).
// Tile 128x128, BK=64, 4 waves (2x2), wave owns 64x64 = 4x4 frags of
// mfma_f32_16x16x32_bf16. global_load_lds staging, swizzled LDS.
// ---------------------------------------------------------------------------
template <bool GELU>
__global__ __launch_bounds__(256) void mgemm128(
    const short* __restrict__ A, const short* __restrict__ Bt,
    const float* __restrict__ bias, short* __restrict__ C, int Nn, int K) {
    __shared__ __align__(16) short As[128 * 64];
    __shared__ __align__(16) short Bs[128 * 64];

    const int tid = threadIdx.x, lane = tid & 63, w = tid >> 6;
    const int wm = (w >> 1) * 64, wn = (w & 1) * 64;
    const int rowBase = blockIdx.y * 128, colBase = blockIdx.x * 128;
    const int lr = lane >> 3, sc = (lane & 7) ^ lr;   // staging row-in-8 / src chunk
    const int fr = lane & 15, g4 = lane >> 4;

    f32x4 acc[4][4];
#pragma unroll
    for (int i = 0; i < 4; ++i)
#pragma unroll
        for (int j = 0; j < 4; ++j) acc[i][j] = f32x4{0.f, 0.f, 0.f, 0.f};

    for (int k0 = 0; k0 < K; k0 += 64) {
#pragma unroll
        for (int i = 0; i < 4; ++i) {
            int g = w * 4 + i;           // 16B-chunk-group: rows g*8..g*8+7
            int row = g * 8 + lr;
            GLOAD16(A  + (size_t)(rowBase + row) * K + k0 + sc * 8, &As[g * 512]);
            GLOAD16(Bt + (size_t)(colBase + row) * K + k0 + sc * 8, &Bs[g * 512]);
        }
        __syncthreads();

#pragma unroll
        for (int kk = 0; kk < 2; ++kk) {
            int j = kk * 4 + g4;
            short8 af[4], bfv[4];
#pragma unroll
            for (int f = 0; f < 4; ++f) {
                af[f]  = *(const short8*)&As[lds_idx(wm + f * 16 + fr, j)];
                bfv[f] = *(const short8*)&Bs[lds_idx(wn + f * 16 + fr, j)];
            }
#pragma unroll
            for (int fm = 0; fm < 4; ++fm)
#pragma unroll
                for (int fn = 0; fn < 4; ++fn)
                    acc[fm][fn] = __builtin_amdgcn_mfma_f32_16x16x32_bf16(
                        af[fm], bfv[fn], acc[fm][fn], 0, 0, 0);
        }
        __syncthreads();
    }

    const int cc = lane & 15, cr = g4 * 4;
#pragma unroll
    for (int fm = 0; fm < 4; ++fm)
#pragma unroll
        for (int fn = 0; fn < 4; ++fn) {
            int c = colBase + wn + fn * 16 + cc;
            float bv = bias[c];
#pragma unroll
            for (int j = 0; j < 4; ++j) {
                int r = rowBase + wm + fm * 16 + cr + j;
                float v = acc[fm][fn][j] + bv;
                if (GELU) v = 0.5f * v * (1.0f + erff(v * 0.70710678118654752f));
                C[(size_t)r * Nn + c] = f2bf(v);
            }
        }
}

// ---------------------------------------------------------------------------
// gemmln: fused C = LN( A @ Bt^T + bias + res ), Nn == 256 (full rows).
// Tile 32x256, BK=64, 4 waves; wave w owns cols [w*64, w*64+64).
// global_load_lds staging, swizzled LDS. Row stats via shfl + LDS.
// ---------------------------------------------------------------------------
template <bool RESBF, bool OUTBF>
__global__ __launch_bounds__(256) void gemmln(
    const short* __restrict__ A, const short* __restrict__ Bt,
    const float* __restrict__ bias, const void* __restrict__ resv,
    const float* __restrict__ gw, const float* __restrict__ bw,
    void* __restrict__ Cv, int K) {
    __shared__ __align__(16) short As[32 * 64];
    __shared__ __align__(16) short Bs[256 * 64];
    __shared__ float red1[4][32], red2[4][32];

    const int tid = threadIdx.x, lane = tid & 63, w = tid >> 6;
    const int rowBase = blockIdx.x * 32;
    const int lr = lane >> 3, sc = (lane & 7) ^ lr;
    const int cc = lane & 15, g4 = lane >> 4;

    f32x4 acc[2][4];
#pragma unroll
    for (int i = 0; i < 2; ++i)
#pragma unroll
        for (int j = 0; j < 4; ++j) acc[i][j] = f32x4{0.f, 0.f, 0.f, 0.f};

    for (int k0 = 0; k0 < K; k0 += 64) {
        {   // A tile: 32 rows, wave w stages rows w*8..w*8+7
            int row = w * 8 + lr;
            GLOAD16(A + (size_t)(rowBase + row) * K + k0 + sc * 8, &As[w * 512]);
        }
#pragma unroll
        for (int i = 0; i < 8; ++i) {   // B tile: 256 rows
            int g = w * 8 + i;
            int row = g * 8 + lr;
            GLOAD16(Bt + (size_t)row * K + k0 + sc * 8, &Bs[g * 512]);
        }
        __syncthreads();

#pragma unroll
        for (int kk = 0; kk < 2; ++kk) {
            int j = kk * 4 + g4;
            short8 af[2], bfv[4];
            af[0] = *(const short8*)&As[lds_idx(cc, j)];
            af[1] = *(const short8*)&As[lds_idx(16 + cc, j)];
#pragma unroll
            for (int fn = 0; fn < 4; ++fn)
                bfv[fn] = *(const short8*)&Bs[lds_idx(w * 64 + fn * 16 + cc, j)];
#pragma unroll
            for (int fm = 0; fm < 2; ++fm)
#pragma unroll
                for (int fn = 0; fn < 4; ++fn)
                    acc[fm][fn] = __builtin_amdgcn_mfma_f32_16x16x32_bf16(
                        af[fm], bfv[fn], acc[fm][fn], 0, 0, 0);
        }
        __syncthreads();
    }

    // epilogue: bias + residual, then row LN over 256 cols
    float v[2][4][4];
    float p1[2][4], p2[2][4];
#pragma unroll
    for (int fm = 0; fm < 2; ++fm)
#pragma unroll
        for (int j = 0; j < 4; ++j) { p1[fm][j] = 0.f; p2[fm][j] = 0.f; }

#pragma unroll
    for (int fm = 0; fm < 2; ++fm)
#pragma unroll
        for (int fn = 0; fn < 4; ++fn) {
            int c = w * 64 + fn * 16 + cc;
            float bv = bias[c];
#pragma unroll
            for (int j = 0; j < 4; ++j) {
                int r = rowBase + fm * 16 + g4 * 4 + j;
                float t = acc[fm][fn][j] + bv;
                if (RESBF) t += bf2f(((const short*)resv)[(size_t)r * 256 + c]);
                else       t += ((const float*)resv)[(size_t)r * 256 + c];
                v[fm][fn][j] = t;
                p1[fm][j] += t;
                p2[fm][j] += t * t;
            }
        }

#pragma unroll
    for (int m = 1; m < 16; m <<= 1) {
#pragma unroll
        for (int fm = 0; fm < 2; ++fm)
#pragma unroll
            for (int j = 0; j < 4; ++j) {
                p1[fm][j] += __shfl_xor(p1[fm][j], m);
                p2[fm][j] += __shfl_xor(p2[fm][j], m);
            }
    }
    if (cc == 0) {
#pragma unroll
        for (int fm = 0; fm < 2; ++fm)
#pragma unroll
            for (int j = 0; j < 4; ++j) {
                red1[w][fm * 16 + g4 * 4 + j] = p1[fm][j];
                red2[w][fm * 16 + g4 * 4 + j] = p2[fm][j];
            }
    }
    __syncthreads();

#pragma unroll
    for (int fm = 0; fm < 2; ++fm)
#pragma unroll
        for (int j = 0; j < 4; ++j) {
            int rl = fm * 16 + g4 * 4 + j;
            int r = rowBase + rl;
            float s1 = red1[0][rl] + red1[1][rl] + red1[2][rl] + red1[3][rl];
            float s2 = red2[0][rl] + red2[1][rl] + red2[2][rl] + red2[3][rl];
            float mu = s1 * (1.0f / 256.0f);
            float var = s2 * (1.0f / 256.0f) - mu * mu;
            float rstd = rsqrtf(var + LNEPS);
#pragma unroll
            for (int fn = 0; fn < 4; ++fn) {
                int c = w * 64 + fn * 16 + cc;
                float o = (v[fm][fn][j] - mu) * rstd * gw[c] + bw[c];
                if (OUTBF) ((short*)Cv)[(size_t)r * 256 + c] = f2bf(o);
                else       ((float*)Cv)[(size_t)r * 256 + c] = o;
            }
        }
}

// ---------------------------------------------------------------------------
// Segment attention on bf16 qkv: one wave per (row, head).
// ---------------------------------------------------------------------------
__global__ __launch_bounds__(256) void attn_kernel(
    const short* __restrict__ qkv, const int* __restrict__ seg_s,
    const int* __restrict__ seg_e, short* __restrict__ attn_out) {
    int h = threadIdx.x >> 6;
    int lane = threadIdx.x & 63;
    int row = blockIdx.x;

    const float qd = bf2f(qkv[(size_t)row * 768 + h * 64 + lane]);
    const int s = seg_s[row], e = seg_e[row];

    float m = -INFINITY, l = 0.0f, acc = 0.0f;
    for (int j = s; j < e; ++j) {
        float kd = bf2f(qkv[(size_t)j * 768 + 256 + h * 64 + lane]);
        float prod = qd * kd;
#pragma unroll
        for (int off = 32; off; off >>= 1) prod += __shfl_xor(prod, off);
        float score = prod * 0.125f;   // 1/sqrt(64)
        float mn = fmaxf(m, score);
        float scale = __expf(m - mn);
        float p = __expf(score - mn);
        l = l * scale + p;
        acc = acc * scale + p * bf2f(qkv[(size_t)j * 768 + 512 + h * 64 + lane]);
        m = mn;
    }
    attn_out[(size_t)row * 256 + h * 64 + lane] = f2bf(acc / l);
}

// ---------------------------------------------------------------------------
extern "C" void kernel_launch(void* const* d_in, const int* in_sizes, int n_in,
                              void* d_out, int out_size, void* d_ws, size_t ws_size,
                              hipStream_t stream) {
    const float* x      = (const float*)d_in[0];
    const int*   dom    = (const int*)d_in[1];
    const float* qkv_w  = (const float*)d_in[2];
    const float* qkv_b  = (const float*)d_in[3];
    const float* out_w  = (const float*)d_in[4];
    const float* out_b  = (const float*)d_in[5];
    const float* ff_w1  = (const float*)d_in[6];
    const float* ff_b1  = (const float*)d_in[7];
    const float* ff_w2  = (const float*)d_in[8];
    const float* ff_b2  = (const float*)d_in[9];
    const float* ln1_g  = (const float*)d_in[10];
    const float* ln1_b  = (const float*)d_in[11];
    const float* ln2_g  = (const float*)d_in[12];
    const float* ln2_b  = (const float*)d_in[13];
    float* out = (float*)d_out;

    short* xB     = (short*)d_ws;                    // NP x 256
    short* qkvB   = xB + (size_t)NP * 256;           // NP x 768
    short* attn_o = qkvB + (size_t)NP * 768;         // NP x 256
    short* x1     = attn_o + (size_t)NP * 256;       // NP x 256
    short* hB     = x1 + (size_t)NP * 256;           // NP x 1024
    short* qkvT   = hB + (size_t)NP * 1024;          // 768 x 256
    short* outT   = qkvT + 768 * 256;                // 256 x 256
    short* ff1T   = outT + 256 * 256;                // 1024 x 256
    short* ff2T   = ff1T + 1024 * 256;               // 256 x 1024
    int* seg_s    = (int*)(ff2T + 256 * 1024);
    int* seg_e    = seg_s + NP;

    // 0) weight transpose/convert + segment bounds + x->bf16 (one launch)
    prep_kernel<<<1560, 256, 0, stream>>>(qkv_w, out_w, ff_w1, ff_w2,
                                          qkvT, outT, ff1T, ff2T,
                                          dom, seg_s, seg_e, x, xB);

    // 1) qkv = x @ qkv_w + qkv_b                (bf16 out)
    mgemm128<false><<<dim3(768 / 128, NP / 128), 256, 0, stream>>>(
        xB, qkvT, qkv_b, qkvB, 768, 256);

    // 2) segment attention
    attn_kernel<<<NP, 256, 0, stream>>>(qkvB, seg_s, seg_e, attn_o);

    // 3) x1 = LN1(x + attn_o @ out_w + out_b)   (bf16 out, fp32 residual)
    gemmln<false, true><<<NP / 32, 256, 0, stream>>>(
        attn_o, outT, out_b, x, ln1_g, ln1_b, x1, 256);

    // 4) h = gelu(x1 @ ff_w1 + ff_b1)           (bf16 out)
    mgemm128<true><<<dim3(DFF / 128, NP / 128), 256, 0, stream>>>(
        x1, ff1T, ff_b1, hB, 1024, 256);

    // 5) out = LN2(x1 + h @ ff_w2 + ff_b2)      (fp32 out, bf16 residual)
    gemmln<true, false><<<NP / 32, 256, 0, stream>>>(
        hB, ff2T, ff_b2, x1, ln2_g, ln2_b, out, 1024);
}